// Round 2
// baseline (589.135 us; speedup 1.0000x reference)
//
#include <hip/hip_runtime.h>

// ---------------------------------------------------------------------------
// LSH attention, MI355X.  B=2, S=2048, E=1024, H=16, Dh=64, NB=64, NH=6.
// ALL inputs/outputs are FP32 (reference is jnp.float32 end to end).
//   0) split_kernel: fp32 -> bf16 hi (+ optional bf16 lo residual)
//   1) gemm_q: Q = x @ Wq^T + bq, 3-term hi/lo bf16 MFMA (~1e-5 accurate)
//      -> Qf fp32 [tok,1024] (buckets), Qb/Qlo bf16 [B,H,S,Dh] (QK^T)
//   2) gemm_v: Vt = (x @ Wv^T + bv)^T, 1-term bf16, stored [B,H,Dh,S]
//   3) bucket_kernel: bucket bits = sign(fp32 q . hyperplanes)
//   4) attn_kernel: flash-style online softmax, logit = (q.q/32)*(62+[same])
// Workspace (62.25 MB):
//   xh 8 | xl 8 | Wqh 2 | Wql 2 | Wvh 2 | Qb 8 | Qlo 8 | Vt 8 | Qf 16 | bkt .25
// ---------------------------------------------------------------------------

typedef short short8 __attribute__((ext_vector_type(8)));
typedef float f32x4 __attribute__((ext_vector_type(4)));
typedef unsigned short us4 __attribute__((ext_vector_type(4)));

__device__ __forceinline__ float bff(unsigned short h) {
    return __uint_as_float(((unsigned int)h) << 16);
}
__device__ __forceinline__ unsigned short f2bf(float f) {  // RNE, finite inputs
    unsigned int u = __float_as_uint(f);
    u += 0x7fffu + ((u >> 16) & 1u);
    return (unsigned short)(u >> 16);
}

// ---------------------------------------------------------------------------
// fp32 -> bf16 hi (+ lo residual).  float4-vectorized.
// ---------------------------------------------------------------------------
__global__ __launch_bounds__(256) void split_kernel(
    const float* __restrict__ in, unsigned short* __restrict__ hi,
    unsigned short* __restrict__ lo, int n4)
{
    const int idx = blockIdx.x * 256 + threadIdx.x;
    if (idx >= n4) return;
    const float4 v = ((const float4*)in)[idx];
    us4 h;
    h.x = f2bf(v.x); h.y = f2bf(v.y); h.z = f2bf(v.z); h.w = f2bf(v.w);
    ((us4*)hi)[idx] = h;
    if (lo) {
        us4 l;
        l.x = f2bf(v.x - bff(h.x)); l.y = f2bf(v.y - bff(h.y));
        l.z = f2bf(v.z - bff(h.z)); l.w = f2bf(v.w - bff(h.w));
        ((us4*)lo)[idx] = l;
    }
}

// ---------------------------------------------------------------------------
// Q-GEMM: C[m,n] = sum_k x[m,k]*Wq[n,k] + bq[n], 3-term hi/lo split.
// 128x128 tile, 4 waves, wave owns 128x32; frags direct from global (L1/L2).
// ---------------------------------------------------------------------------
__global__ __launch_bounds__(256) void gemm_q(
    const unsigned short* __restrict__ xh, const unsigned short* __restrict__ xl,
    const unsigned short* __restrict__ wh, const unsigned short* __restrict__ wl,
    const float* __restrict__ bias, float* __restrict__ Qf,
    unsigned short* __restrict__ Qb, unsigned short* __restrict__ Qlo)
{
    const int tid = threadIdx.x;
    const int w = tid >> 6, lane = tid & 63;
    const int i = lane & 15, qd = lane >> 4;
    const int m0 = blockIdx.x * 128;
    const int nb = blockIdx.y * 128 + w * 32;

    f32x4 acc[8][2];
#pragma unroll
    for (int a = 0; a < 8; ++a)
#pragma unroll
        for (int b2 = 0; b2 < 2; ++b2) acc[a][b2] = f32x4{0.f, 0.f, 0.f, 0.f};

    const unsigned short* aph = xh + (size_t)(m0 + i) * 1024 + qd * 8;
    const unsigned short* apl = xl + (size_t)(m0 + i) * 1024 + qd * 8;
    const unsigned short* bph = wh + (size_t)(nb + i) * 1024 + qd * 8;
    const unsigned short* bpl = wl + (size_t)(nb + i) * 1024 + qd * 8;

    for (int k0 = 0; k0 < 1024; k0 += 32) {
        short8 ah[8], al[8], bh2[2], bl2[2];
#pragma unroll
        for (int mm = 0; mm < 8; ++mm) {
            ah[mm] = *(const short8*)(aph + (size_t)mm * 16 * 1024 + k0);
            al[mm] = *(const short8*)(apl + (size_t)mm * 16 * 1024 + k0);
        }
#pragma unroll
        for (int nn = 0; nn < 2; ++nn) {
            bh2[nn] = *(const short8*)(bph + (size_t)nn * 16 * 1024 + k0);
            bl2[nn] = *(const short8*)(bpl + (size_t)nn * 16 * 1024 + k0);
        }
#pragma unroll
        for (int mm = 0; mm < 8; ++mm)
#pragma unroll
            for (int nn = 0; nn < 2; ++nn) {
                acc[mm][nn] = __builtin_amdgcn_mfma_f32_16x16x32_bf16(
                    ah[mm], bh2[nn], acc[mm][nn], 0, 0, 0);
                acc[mm][nn] = __builtin_amdgcn_mfma_f32_16x16x32_bf16(
                    al[mm], bh2[nn], acc[mm][nn], 0, 0, 0);
                acc[mm][nn] = __builtin_amdgcn_mfma_f32_16x16x32_bf16(
                    ah[mm], bl2[nn], acc[mm][nn], 0, 0, 0);
            }
    }

    // C layout: col = i (lane&15), row = qd*4 + reg  [m89-verified].
#pragma unroll
    for (int mm = 0; mm < 8; ++mm)
#pragma unroll
        for (int nn = 0; nn < 2; ++nn)
#pragma unroll
            for (int rr = 0; rr < 4; ++rr) {
                const int row = m0 + mm * 16 + qd * 4 + rr;  // token b*2048+s
                const int col = nb + nn * 16 + i;            // channel h*64+d
                const float v = acc[mm][nn][rr] + bias[col];
                Qf[(size_t)row * 1024 + col] = v;
                const unsigned short hs = f2bf(v);
                const float lo = v - bff(hs);
                const int b = row >> 11, s = row & 2047;
                const int hh = col >> 6, d = col & 63;
                const size_t oi = ((size_t)((b << 4) + hh) * 2048 + s) * 64 + d;
                Qb[oi] = hs;
                Qlo[oi] = f2bf(lo);
            }
}

// ---------------------------------------------------------------------------
// V-GEMM (pre-transposed output): A = Wvh [1024 ch, K], B = xh [4096 tok, K];
// C[ch, tok] + bv[ch] -> Vt[b][ch][s].  1-term bf16 (0.3% acc is plenty).
// ---------------------------------------------------------------------------
__global__ __launch_bounds__(256) void gemm_v(
    const unsigned short* __restrict__ wh, const unsigned short* __restrict__ xh,
    const float* __restrict__ bias, unsigned short* __restrict__ Vt)
{
    const int tid = threadIdx.x;
    const int w = tid >> 6, lane = tid & 63;
    const int i = lane & 15, qd = lane >> 4;
    const int m0 = blockIdx.x * 128;           // channel tile
    const int nb = blockIdx.y * 128 + w * 32;  // token tile

    f32x4 acc[8][2];
#pragma unroll
    for (int a = 0; a < 8; ++a)
#pragma unroll
        for (int b2 = 0; b2 < 2; ++b2) acc[a][b2] = f32x4{0.f, 0.f, 0.f, 0.f};

    const unsigned short* ap = wh + (size_t)(m0 + i) * 1024 + qd * 8;
    const unsigned short* bp = xh + (size_t)(nb + i) * 1024 + qd * 8;

    for (int k0 = 0; k0 < 1024; k0 += 32) {
        short8 af[8], bf2[2];
#pragma unroll
        for (int mm = 0; mm < 8; ++mm)
            af[mm] = *(const short8*)(ap + (size_t)mm * 16 * 1024 + k0);
#pragma unroll
        for (int nn = 0; nn < 2; ++nn)
            bf2[nn] = *(const short8*)(bp + (size_t)nn * 16 * 1024 + k0);
#pragma unroll
        for (int mm = 0; mm < 8; ++mm)
#pragma unroll
            for (int nn = 0; nn < 2; ++nn)
                acc[mm][nn] = __builtin_amdgcn_mfma_f32_16x16x32_bf16(
                    af[mm], bf2[nn], acc[mm][nn], 0, 0, 0);
    }

#pragma unroll
    for (int mm = 0; mm < 8; ++mm)
#pragma unroll
        for (int nn = 0; nn < 2; ++nn)
#pragma unroll
            for (int rr = 0; rr < 4; ++rr) {
                const int rch = m0 + mm * 16 + qd * 4 + rr;  // channel h*64+d
                const int tok = nb + nn * 16 + i;            // token b*2048+s
                const float v = acc[mm][nn][rr] + bias[rch];
                const int b = tok >> 11, s = tok & 2047;
                Vt[((size_t)(b * 1024 + rch)) * 2048 + s] = f2bf(v);
            }
}

// ---------------------------------------------------------------------------
// Buckets from fp32 q: proj_n = sum_d q[d]*hp[d][n] + hp[64][n] (ones col);
// bucket = sum_n (proj_n >= 0) << n.  One thread per (token, head).
// ---------------------------------------------------------------------------
__global__ __launch_bounds__(256) void bucket_kernel(
    const float* __restrict__ Qf, const float* __restrict__ hp,
    int* __restrict__ buckets)
{
    __shared__ float hpl[65 * 6];
    const int tid = threadIdx.x;
    if (tid < 65 * 6) hpl[tid] = hp[tid];
    __syncthreads();

    const int idx = blockIdx.x * 256 + tid;       // 65536 total
    const int m = idx >> 4, h = idx & 15;
    const float* qrow = Qf + (size_t)m * 1024 + h * 64;

    float pj[6];
#pragma unroll
    for (int n = 0; n < 6; ++n) pj[n] = hpl[64 * 6 + n];
    for (int d = 0; d < 64; ++d) {
        const float qv = qrow[d];
#pragma unroll
        for (int n = 0; n < 6; ++n) pj[n] = fmaf(qv, hpl[d * 6 + n], pj[n]);
    }
    int bkt = 0;
#pragma unroll
    for (int n = 0; n < 6; ++n) bkt |= (pj[n] >= 0.f) << n;
    buckets[((m >> 11) * 16 + h) * 2048 + (m & 2047)] = bkt;
}

// ---------------------------------------------------------------------------
// Attention.  Grid (bh=32, qtile=32), bh fastest -> ~4 bh per XCD in L2.
// Block 256 = 4 waves; wave owns 16 q-rows; key tile 64; hi/lo QK^T (3 terms
// x 2 K-chunks); P via per-wave XOR-swizzled LDS; fp32 output.
// ---------------------------------------------------------------------------
__global__ __launch_bounds__(256) void attn_kernel(
    const unsigned short* __restrict__ Qb, const unsigned short* __restrict__ Qlo,
    const unsigned short* __restrict__ Vt, const int* __restrict__ bks,
    float* __restrict__ out)
{
    __shared__ unsigned short P[4][16 * 64];

    const int tid = threadIdx.x;
    const int w = tid >> 6, lane = tid & 63;
    const int i = lane & 15, qd = lane >> 4;
    const int bh = blockIdx.x;
    const int q0 = blockIdx.y * 64 + w * 16;

    const unsigned short* Qh = Qb + (size_t)bh * 2048 * 64;
    const unsigned short* Ql = Qlo + (size_t)bh * 2048 * 64;
    const unsigned short* Vb = Vt + (size_t)bh * 64 * 2048;
    const int* bk = bks + bh * 2048;
    unsigned short* Pw = &P[w][0];

    // Q A-frags (reused across all key tiles): row = q0+i, k = qd*8 (+32)
    const unsigned short* qp = Qh + (size_t)(q0 + i) * 64 + qd * 8;
    const unsigned short* lp = Ql + (size_t)(q0 + i) * 64 + qd * 8;
    const short8 aqh0 = *(const short8*)qp, aqh1 = *(const short8*)(qp + 32);
    const short8 aql0 = *(const short8*)lp, aql1 = *(const short8*)(lp + 32);

    int qbr[4];
#pragma unroll
    for (int r = 0; r < 4; ++r) qbr[r] = bk[q0 + qd * 4 + r];

    f32x4 o[4];
#pragma unroll
    for (int d = 0; d < 4; ++d) o[d] = f32x4{0.f, 0.f, 0.f, 0.f};
    float mrun[4] = {-1e30f, -1e30f, -1e30f, -1e30f};
    float lrun[4] = {0.f, 0.f, 0.f, 0.f};

    for (int t0 = 0; t0 < 2048; t0 += 64) {
        f32x4 s[4];
        int kb[4];
#pragma unroll
        for (int sub = 0; sub < 4; ++sub) {
            const int kr = t0 + sub * 16 + i;
            const unsigned short* kh = Qh + (size_t)kr * 64 + qd * 8;
            const unsigned short* kl = Ql + (size_t)kr * 64 + qd * 8;
            const short8 bh0 = *(const short8*)kh, bh1 = *(const short8*)(kh + 32);
            const short8 bl0 = *(const short8*)kl, bl1 = *(const short8*)(kl + 32);
            f32x4 t = f32x4{0.f, 0.f, 0.f, 0.f};
            t = __builtin_amdgcn_mfma_f32_16x16x32_bf16(aqh0, bh0, t, 0, 0, 0);
            t = __builtin_amdgcn_mfma_f32_16x16x32_bf16(aqh1, bh1, t, 0, 0, 0);
            t = __builtin_amdgcn_mfma_f32_16x16x32_bf16(aql0, bh0, t, 0, 0, 0);
            t = __builtin_amdgcn_mfma_f32_16x16x32_bf16(aql1, bh1, t, 0, 0, 0);
            t = __builtin_amdgcn_mfma_f32_16x16x32_bf16(aqh0, bl0, t, 0, 0, 0);
            t = __builtin_amdgcn_mfma_f32_16x16x32_bf16(aqh1, bl1, t, 0, 0, 0);
            s[sub] = t;
            kb[sub] = bk[t0 + sub * 16 + i];
        }

        // logits + online softmax.  C layout: col = sub*16+i, row = qd*4+r.
        float lg[4][4];
        float mt[4] = {-1e30f, -1e30f, -1e30f, -1e30f};
#pragma unroll
        for (int sub = 0; sub < 4; ++sub)
#pragma unroll
            for (int r = 0; r < 4; ++r) {
                const float c = (kb[sub] == qbr[r]) ? 63.f : 62.f;
                const float v = s[sub][r] * 0.03125f * c;
                lg[sub][r] = v;
                mt[r] = fmaxf(mt[r], v);
            }
#pragma unroll
        for (int r = 0; r < 4; ++r) {
#pragma unroll
            for (int msk = 1; msk < 16; msk <<= 1)
                mt[r] = fmaxf(mt[r], __shfl_xor(mt[r], msk));
        }
        float alpha[4], lt[4];
#pragma unroll
        for (int r = 0; r < 4; ++r) {
            const float mn = fmaxf(mrun[r], mt[r]);
            alpha[r] = __expf(mrun[r] - mn);
            mrun[r] = mn;
            lt[r] = 0.f;
        }
#pragma unroll
        for (int sub = 0; sub < 4; ++sub)
#pragma unroll
            for (int r = 0; r < 4; ++r) {
                const float p = __expf(lg[sub][r] - mrun[r]);
                lg[sub][r] = p;
                lt[r] += p;
            }
#pragma unroll
        for (int r = 0; r < 4; ++r) {
#pragma unroll
            for (int msk = 1; msk < 16; msk <<= 1)
                lt[r] += __shfl_xor(lt[r], msk);
            lrun[r] = lrun[r] * alpha[r] + lt[r];
        }
#pragma unroll
        for (int d = 0; d < 4; ++d)
#pragma unroll
            for (int r = 0; r < 4; ++r) o[d][r] *= alpha[r];

        // P -> LDS, XOR-swizzled 16B granules:
        //   elem(row,col) at row*64 + ((col>>3) ^ (row&7))*8 + (col&7)
#pragma unroll
        for (int sub = 0; sub < 4; ++sub)
#pragma unroll
            for (int r = 0; r < 4; ++r) {
                const int row = qd * 4 + r, col = sub * 16 + i;
                Pw[row * 64 + (((col >> 3) ^ (row & 7)) << 3) + (col & 7)] =
                    f2bf(lg[sub][r]);
            }
        // A-frag of P: row = i, k-granules qd and qd+4 (wave-local, no barrier)
        const short8 pa0 = *(const short8*)&Pw[i * 64 + ((qd ^ (i & 7)) << 3)];
        const short8 pa1 = *(const short8*)&Pw[i * 64 + (((qd + 4) ^ (i & 7)) << 3)];

#pragma unroll
        for (int dsub = 0; dsub < 4; ++dsub) {
            const unsigned short* vp =
                Vb + (size_t)(dsub * 16 + i) * 2048 + t0 + qd * 8;
            const short8 vb0 = *(const short8*)vp;
            const short8 vb1 = *(const short8*)(vp + 32);
            o[dsub] = __builtin_amdgcn_mfma_f32_16x16x32_bf16(pa0, vb0, o[dsub], 0, 0, 0);
            o[dsub] = __builtin_amdgcn_mfma_f32_16x16x32_bf16(pa1, vb1, o[dsub], 0, 0, 0);
        }
    }

    // Epilogue: out[b][s][h*64+d] fp32; s = q0+qd*4+r, d = dsub*16+i
    const int b = bh >> 4, h = bh & 15;
#pragma unroll
    for (int dsub = 0; dsub < 4; ++dsub)
#pragma unroll
        for (int r = 0; r < 4; ++r) {
            const float v = o[dsub][r] / lrun[r];
            const int srow = q0 + qd * 4 + r;
            out[((size_t)(b * 2048 + srow)) * 1024 + h * 64 + dsub * 16 + i] = v;
        }
}

// ---------------------------------------------------------------------------
extern "C" void kernel_launch(void* const* d_in, const int* in_sizes, int n_in,
                              void* d_out, int out_size, void* d_ws, size_t ws_size,
                              hipStream_t stream)
{
    const float* x  = (const float*)d_in[0];
    const float* Wq = (const float*)d_in[1];
    const float* bq = (const float*)d_in[2];
    const float* Wv = (const float*)d_in[3];
    const float* bv = (const float*)d_in[4];
    const float* hp = (const float*)d_in[5];
    float* out = (float*)d_out;

    char* ws = (char*)d_ws;
    const size_t MB = (size_t)1 << 20;
    unsigned short* xh  = (unsigned short*)(ws);            // 8 MB
    unsigned short* xl  = (unsigned short*)(ws + 8 * MB);   // 8 MB
    unsigned short* Wqh = (unsigned short*)(ws + 16 * MB);  // 2 MB
    unsigned short* Wql = (unsigned short*)(ws + 18 * MB);  // 2 MB
    unsigned short* Wvh = (unsigned short*)(ws + 20 * MB);  // 2 MB
    unsigned short* Qb  = (unsigned short*)(ws + 22 * MB);  // 8 MB
    unsigned short* Qlo = (unsigned short*)(ws + 30 * MB);  // 8 MB
    unsigned short* Vt  = (unsigned short*)(ws + 38 * MB);  // 8 MB
    float*          Qf  = (float*)(ws + 46 * MB);           // 16 MB
    int*        buckets = (int*)(ws + 62 * MB);             // 256 KB

    split_kernel<<<dim3(4096), 256, 0, stream>>>(x, xh, xl, 1048576);
    split_kernel<<<dim3(1024), 256, 0, stream>>>(Wq, Wqh, Wql, 262144);
    split_kernel<<<dim3(1024), 256, 0, stream>>>(Wv, Wvh, nullptr, 262144);

    gemm_q<<<dim3(32, 8), 256, 0, stream>>>(xh, xl, Wqh, Wql, bq, Qf, Qb, Qlo);
    gemm_v<<<dim3(8, 32), 256, 0, stream>>>(Wvh, xh, bv, Vt);
    bucket_kernel<<<dim3(256), 256, 0, stream>>>(Qf, hp, buckets);
    attn_kernel<<<dim3(32, 32), 256, 0, stream>>>(Qb, Qlo, Vt, buckets, out);
}